// Round 2
// baseline (413.605 us; speedup 1.0000x reference)
//
#include <hip/hip_runtime.h>

#define D 64
#define KCODES 1024
#define PTS_PER_BLK 128
#define MTILES 8        // 8 M-tiles of 16 points = 128 points/block
#define NT 8            // N-tiles (of 16 codes) per chunk -> 128 codes/chunk
#define NCHUNK 2        // 2 chunks/wave -> 256 codes/wave, 1024/block
#define WL_CAP 4096

typedef short bf16x8 __attribute__((ext_vector_type(8)));
typedef float f32x4 __attribute__((ext_vector_type(4)));

static __device__ __forceinline__ short f2bf(float f) {  // RNE fp32->bf16
  unsigned u = __float_as_uint(f);
  u += 0x7FFF + ((u >> 16) & 1);
  return (short)(u >> 16);
}

// Exact fp32 distance, bit-identical to the original formula (4-chain fma, then
// fma(-2,dot,fn2)+en2). Packed-key atomicMin: ties -> smaller idx = first occurrence.
static __device__ __forceinline__ void evalExact(const float* __restrict__ inputs,
                                                 const float* __restrict__ embedT,
                                                 const float* __restrict__ en2,
                                                 const float* s_fn2,
                                                 int p0blk, int pl, int c,
                                                 unsigned long long* s_best) {
  int p = p0blk + pl;
  const float* f = inputs + (size_t)p * D;
  const float* e = embedT + (size_t)c * D;
  float a0 = 0.f, a1 = 0.f, a2 = 0.f, a3 = 0.f;
#pragma unroll
  for (int d = 0; d < D; d += 4) {
    a0 = fmaf(f[d + 0], e[d + 0], a0);
    a1 = fmaf(f[d + 1], e[d + 1], a1);
    a2 = fmaf(f[d + 2], e[d + 2], a2);
    a3 = fmaf(f[d + 3], e[d + 3], a3);
  }
  float dot = (a0 + a1) + (a2 + a3);
  float dist = fmaf(-2.f, dot, s_fn2[pl]) + en2[c];
  unsigned long long key = ((unsigned long long)__float_as_uint(dist) << 32) | (unsigned)c;
  atomicMin(&s_best[pl], key);
}

// K0: embed [64][1024] -> embedT fp32 [1024][64], embedTb bf16 [1024][64],
// en2[k] (sequential-fma order), en2max (atomicMax on bits).
__global__ void __launch_bounds__(256) vq_prep_codes(const float* __restrict__ embed,
                                                     float* __restrict__ embedT,
                                                     unsigned short* __restrict__ embedTb,
                                                     float* __restrict__ en2,
                                                     int* __restrict__ en2max_bits) {
  int k = blockIdx.x * 256 + threadIdx.x;
  float row[D];
  float s = 0.f;
#pragma unroll
  for (int d = 0; d < D; ++d) {
    float e = embed[d * KCODES + k];   // coalesced along k
    row[d] = e;
    s = fmaf(e, e, s);
  }
  en2[k] = s;
  float4* o4 = reinterpret_cast<float4*>(embedT + (size_t)k * D);
#pragma unroll
  for (int j = 0; j < 16; ++j)
    o4[j] = make_float4(row[4 * j], row[4 * j + 1], row[4 * j + 2], row[4 * j + 3]);
  unsigned us[32];
#pragma unroll
  for (int j = 0; j < 32; ++j) {
    unsigned lo = (unsigned short)f2bf(row[2 * j]);
    unsigned hi = (unsigned short)f2bf(row[2 * j + 1]);
    us[j] = lo | (hi << 16);
  }
  uint4* ob = reinterpret_cast<uint4*>(embedTb + (size_t)k * D);
#pragma unroll
  for (int j = 0; j < 8; ++j) ob[j] = make_uint4(us[4 * j], us[4 * j + 1], us[4 * j + 2], us[4 * j + 3]);
  float m = s;
#pragma unroll
  for (int off = 32; off; off >>= 1) m = fmaxf(m, __shfl_down(m, off, 64));
  if ((threadIdx.x & 63) == 0) atomicMax(en2max_bits, __float_as_int(m));
}

// K1: per block: 128 points x all 1024 codes.
// R2 changes (occupancy round):
//  - PTS_PER_BLK 256->128, grid 512->1024 blocks (4 blocks/CU possible)
//  - wave's 256 codes processed in 2 chunks of 128 (NT=8): B-frag regs 128->64
//    VGPR, acc 64->32 AGPR -> target <=128 unified regs = 4 waves/SIMD
//  - A-prefetch dropped (reg budget; TLP from 16 waves/CU hides the latency)
//  - out_codes inputs-half written in the fn2 prologue (row already in regs)
//    -> no frow re-read in the epilogue
//  - non-temporal stores REVERTED (R1: +23% WRITE_SIZE, no FETCH gain)
__global__ void __launch_bounds__(256, 4) vq_main_kernel(
    const float* __restrict__ inputs, const float* __restrict__ embedT,
    const unsigned short* __restrict__ embedTb, const float* __restrict__ en2,
    const int* __restrict__ en2max_bits,
    float* __restrict__ out_q, float* __restrict__ out_codes,
    float* __restrict__ out_idx) {
  __shared__ unsigned long long s_best[PTS_PER_BLK];
  __shared__ unsigned s_wl[WL_CAP];
  __shared__ int s_wcount;
  __shared__ float s_fn2[PTS_PER_BLK];

  const int tid = threadIdx.x;
  const int w = tid >> 6;
  const int l = tid & 63;
  const int l15 = l & 15;
  const int lg = l >> 4;                 // quad-group 0..3
  const int p0blk = blockIdx.x * PTS_PER_BLK;

  if (tid < PTS_PER_BLK) s_best[tid] = ~0ull;
  if (tid == 0) s_wcount = 0;

  // Fused fn2 (threads 0..127, one per point): same float4 sequential-fma order
  // as the original vq_prep_fn2 -> bit-identical values. The row is in registers
  // anyway, so also emit the out_codes inputs-half here (saves a 33.5MB re-read).
  if (tid < PTS_PER_BLK) {
    const int p = p0blk + tid;
    const float4* i4 = reinterpret_cast<const float4*>(inputs + (size_t)p * D);
    float4* oc0 = reinterpret_cast<float4*>(out_codes + (size_t)p * 2 * D);
    float s = 0.f;
#pragma unroll
    for (int j = 0; j < 16; ++j) {
      float4 v = i4[j];
      oc0[j] = v;
      s = fmaf(v.x, v.x, s); s = fmaf(v.y, v.y, s);
      s = fmaf(v.z, v.z, s); s = fmaf(v.w, v.w, s);
    }
    s_fn2[tid] = s;
  }

  const float en2max = __int_as_float(*en2max_bits);

  __syncthreads();  // s_best / s_wcount / s_fn2 ready

#pragma unroll 1
  for (int ch = 0; ch < NCHUNK; ++ch) {
    const int cb = w * 256 + ch * 128;   // this wave+chunk's first code

    // B fragments: B[k][n], lane holds n = cb+16t+l15, k = kf*32 + lg*8 + j.
    // embedTb row n is contiguous in k -> one 16B load per frag. L2-hot.
    bf16x8 bfr[NT][2];
    float en2v[NT];
#pragma unroll
    for (int t = 0; t < NT; ++t) {
      const bf16x8* bp = reinterpret_cast<const bf16x8*>(
          embedTb + (size_t)(cb + 16 * t + l15) * D + lg * 8);
      bfr[t][0] = bp[0];   // k in [lg*8, lg*8+8)
      bfr[t][1] = bp[4];   // +32 shorts -> k in [32+lg*8, ...)
      en2v[t] = en2[cb + 16 * t + l15];
    }

#pragma unroll 1
    for (int mt = 0; mt < MTILES; ++mt) {
      const int p0 = p0blk + mt * 16;
      // A fragment: lane holds m = p0+l15, k = kf*32 + lg*8 + j (fp32->bf16 inline).
      const float* arow = inputs + (size_t)(p0 + l15) * D + lg * 8;
      float4 a0 = *reinterpret_cast<const float4*>(arow + 0);
      float4 a1 = *reinterpret_cast<const float4*>(arow + 4);
      float4 a2 = *reinterpret_cast<const float4*>(arow + 32);
      float4 a3 = *reinterpret_cast<const float4*>(arow + 36);
      bf16x8 af0, af1;
      af0[0] = f2bf(a0.x); af0[1] = f2bf(a0.y); af0[2] = f2bf(a0.z); af0[3] = f2bf(a0.w);
      af0[4] = f2bf(a1.x); af0[5] = f2bf(a1.y); af0[6] = f2bf(a1.z); af0[7] = f2bf(a1.w);
      af1[0] = f2bf(a2.x); af1[1] = f2bf(a2.y); af1[2] = f2bf(a2.z); af1[3] = f2bf(a2.w);
      af1[4] = f2bf(a3.x); af1[5] = f2bf(a3.y); af1[6] = f2bf(a3.z); af1[7] = f2bf(a3.w);

      f32x4 acc[NT];
#pragma unroll
      for (int t = 0; t < NT; ++t) acc[t] = (f32x4){0.f, 0.f, 0.f, 0.f};
#pragma unroll
      for (int t = 0; t < NT; ++t)
        acc[t] = __builtin_amdgcn_mfma_f32_16x16x32_bf16(af0, bfr[t][0], acc[t], 0, 0, 0);
#pragma unroll
      for (int t = 0; t < NT; ++t)
        acc[t] = __builtin_amdgcn_mfma_f32_16x16x32_bf16(af1, bfr[t][1], acc[t], 0, 0, 0);

      // C/D layout: row(point) = lg*4 + reg, col(code) = l15 [m89/m91-verified].
      float fnv[4];
#pragma unroll
      for (int r = 0; r < 4; ++r) fnv[r] = s_fn2[mt * 16 + lg * 4 + r];
#pragma unroll
      for (int t = 0; t < NT; ++t)
#pragma unroll
        for (int r = 0; r < 4; ++r)
          acc[t][r] = fmaf(-2.f, acc[t][r], fnv[r]) + en2v[t];

      // Per-WAVE(-chunk) screening min per point. Correctness: the true argmin
      // c* lies in some wave's some chunk; there d~(c*) <= local_min + 2e, so
      // local_min + margin (margin >= 2e) still admits it. No barrier needed.
      float thr[4];
#pragma unroll
      for (int r = 0; r < 4; ++r) {
        float mm = acc[0][r];
#pragma unroll
        for (int t = 1; t < NT; ++t) mm = fminf(mm, acc[t][r]);
#pragma unroll
        for (int s = 1; s < 16; s <<= 1) mm = fminf(mm, __shfl_xor(mm, s, 16));
        // margin >= 2*|d~ - d| bound: bf16 u=2^-8 -> 2*2^-7*sqrt(fn2*en2) + slack, x2 safety.
        thr[r] = mm + (0.03125f * sqrtf(fnv[r] * en2max) + 0.01f);
      }
#pragma unroll
      for (int t = 0; t < NT; ++t)
#pragma unroll
        for (int r = 0; r < 4; ++r)
          if (acc[t][r] <= thr[r]) {
            int pl = mt * 16 + lg * 4 + r;
            int c = cb + 16 * t + l15;
            int pos = atomicAdd(&s_wcount, 1);
            if (pos < WL_CAP) s_wl[pos] = (unsigned)((pl << 10) | c);
            else evalExact(inputs, embedT, en2, s_fn2, p0blk, pl, c, s_best);  // overflow
          }
    }
  }

  __syncthreads();  // worklist complete

  // Exact re-eval of the worklist (parallel across the block).
  int wc = s_wcount; if (wc > WL_CAP) wc = WL_CAP;
  for (int i = tid; i < wc; i += 256)
    evalExact(inputs, embedT, en2, s_fn2, p0blk, (int)(s_wl[i] >> 10), (int)(s_wl[i] & 1023), s_best);
  __syncthreads();

  // Outputs: 4 lanes cooperate per point; inputs-half of out_codes already
  // written in the prologue, so only the quantized row (gathered from embedT,
  // L2-resident) is needed here.
  const int sub = tid & 3;
#pragma unroll 1
  for (int pass = 0; pass < 2; ++pass) {
    int pl = pass * 64 + (tid >> 2);
    unsigned long long key = s_best[pl];
    int c = (int)(unsigned)(key & 0xFFFFFFFFu);
    int p = p0blk + pl;
    const f32x4* qrow = reinterpret_cast<const f32x4*>(embedT + (size_t)c * D);
    f32x4* oq = reinterpret_cast<f32x4*>(out_q + (size_t)p * D);
    f32x4* oc = reinterpret_cast<f32x4*>(out_codes + (size_t)p * 2 * D);
#pragma unroll
    for (int j = 0; j < 4; ++j) {
      int i4 = j * 4 + sub;
      f32x4 qv = qrow[i4];
      oq[i4] = qv;
      oc[16 + i4] = qv;
    }
    if (sub == 0) out_idx[p] = (float)c;
  }
}

extern "C" void kernel_launch(void* const* d_in, const int* in_sizes, int n_in,
                              void* d_out, int out_size, void* d_ws, size_t ws_size,
                              hipStream_t stream) {
  const float* inputs = (const float*)d_in[0];
  const float* embed  = (const float*)d_in[1];
  int N = in_sizes[0] / D;  // 131072

  float* embedT          = (float*)d_ws;                             // 256 KB
  unsigned short* embedTb = (unsigned short*)(embedT + KCODES * D);  // 128 KB
  float* en2             = (float*)(embedTb + KCODES * D);           // 4 KB
  float* fn2_unused      = en2 + KCODES;                             // 512 KB (reserved, unused)
  int* en2max_bits       = (int*)(fn2_unused + N);                   // 4 B

  float* out = (float*)d_out;
  float* out_q     = out;                      // [N, 64]
  float* out_codes = out + (size_t)N * D;      // [N, 128]
  float* out_idx   = out + (size_t)N * D * 3;  // [N]

  vq_prep_codes<<<KCODES / 256, 256, 0, stream>>>(embed, embedT, embedTb, en2, en2max_bits);
  vq_main_kernel<<<N / PTS_PER_BLK, 256, 0, stream>>>(inputs, embedT, embedTb, en2,
                                                      en2max_bits, out_q, out_codes, out_idx);
}

// Round 3
// 340.576 us; speedup vs baseline: 1.2144x; 1.2144x over previous
//
#include <hip/hip_runtime.h>

#define D 64
#define KCODES 1024
#define PTS_PER_BLK 256
#define MTILES 16        // 16 points per M-tile x 16 tiles = 256 points/block
#define NT 4             // 4 N-tiles of 16 codes per wave = 64 codes/wave, 256/block
#define CODE_CHUNKS 4    // 4 blocks cover the 1024 codes for one point-tile
#define PTILES 512       // N / PTS_PER_BLK
#define WL_CAP 4096

typedef short bf16x8 __attribute__((ext_vector_type(8)));
typedef float f32x4 __attribute__((ext_vector_type(4)));

static __device__ __forceinline__ short f2bf(float f) {  // RNE fp32->bf16
  unsigned u = __float_as_uint(f);
  u += 0x7FFF + ((u >> 16) & 1);
  return (short)(u >> 16);
}

// Exact fp32 distance, bit-identical to the original formula (4-chain fma, then
// fma(-2,dot,fn2)+en2). Packed-key atomicMin: ties -> smaller idx = first occurrence.
static __device__ __forceinline__ void evalExact(const float* __restrict__ inputs,
                                                 const float* __restrict__ embedT,
                                                 const float* __restrict__ en2,
                                                 const float* s_fn2,
                                                 int p0blk, int pl, int c,
                                                 unsigned long long* s_best) {
  int p = p0blk + pl;
  const float* f = inputs + (size_t)p * D;
  const float* e = embedT + (size_t)c * D;
  float a0 = 0.f, a1 = 0.f, a2 = 0.f, a3 = 0.f;
#pragma unroll
  for (int d = 0; d < D; d += 4) {
    a0 = fmaf(f[d + 0], e[d + 0], a0);
    a1 = fmaf(f[d + 1], e[d + 1], a1);
    a2 = fmaf(f[d + 2], e[d + 2], a2);
    a3 = fmaf(f[d + 3], e[d + 3], a3);
  }
  float dot = (a0 + a1) + (a2 + a3);
  float dist = fmaf(-2.f, dot, s_fn2[pl]) + en2[c];
  unsigned long long key = ((unsigned long long)__float_as_uint(dist) << 32) | (unsigned)c;
  atomicMin(&s_best[pl], key);
}

// Merged prep. Blocks 0..3: embed [64][1024] -> embedT fp32 [1024][64],
// embedTb bf16 [1024][64], en2[k] (sequential-fma order), en2max (atomicMax
// on bits; ws poison is a negative int so any positive value wins).
// Blocks 4..515: fn2[p] (original float4 sequential-fma order -> bit-identical)
// and best[p] = ~0ull init.
__global__ void __launch_bounds__(256) vq_prep(const float* __restrict__ embed,
                                               const float* __restrict__ inputs,
                                               float* __restrict__ embedT,
                                               unsigned short* __restrict__ embedTb,
                                               float* __restrict__ en2,
                                               int* __restrict__ en2max_bits,
                                               float* __restrict__ fn2,
                                               unsigned long long* __restrict__ best) {
  const int bid = blockIdx.x;
  const int tid = threadIdx.x;
  if (bid < KCODES / 256) {
    int k = bid * 256 + tid;
    float row[D];
    float s = 0.f;
#pragma unroll
    for (int d = 0; d < D; ++d) {
      float e = embed[d * KCODES + k];   // coalesced along k
      row[d] = e;
      s = fmaf(e, e, s);
    }
    en2[k] = s;
    float4* o4 = reinterpret_cast<float4*>(embedT + (size_t)k * D);
#pragma unroll
    for (int j = 0; j < 16; ++j)
      o4[j] = make_float4(row[4 * j], row[4 * j + 1], row[4 * j + 2], row[4 * j + 3]);
    unsigned us[32];
#pragma unroll
    for (int j = 0; j < 32; ++j) {
      unsigned lo = (unsigned short)f2bf(row[2 * j]);
      unsigned hi = (unsigned short)f2bf(row[2 * j + 1]);
      us[j] = lo | (hi << 16);
    }
    uint4* ob = reinterpret_cast<uint4*>(embedTb + (size_t)k * D);
#pragma unroll
    for (int j = 0; j < 8; ++j)
      ob[j] = make_uint4(us[4 * j], us[4 * j + 1], us[4 * j + 2], us[4 * j + 3]);
    float m = s;
#pragma unroll
    for (int off = 32; off; off >>= 1) m = fmaxf(m, __shfl_down(m, off, 64));
    if ((tid & 63) == 0) atomicMax(en2max_bits, __float_as_int(m));
  } else {
    int p = (bid - KCODES / 256) * 256 + tid;
    const float4* i4 = reinterpret_cast<const float4*>(inputs + (size_t)p * D);
    float s = 0.f;
#pragma unroll
    for (int j = 0; j < 16; ++j) {
      float4 v = i4[j];
      s = fmaf(v.x, v.x, s); s = fmaf(v.y, v.y, s);
      s = fmaf(v.z, v.z, s); s = fmaf(v.w, v.w, s);
    }
    fn2[p] = s;
    best[p] = ~0ull;
  }
}

// K1 (partial): block = (code-chunk, point-tile); 256 points x 256 codes.
// chunk-slow block order: bid = chunk*PTILES + ptile, so consecutive blocks
// share the 32KB table chunk (L2-hot) and the 4 visits to a point-tile land
// on the same XCD (ptile%8 invariant: PTILES%8==0).
// R0's tight block-global screen is restored (min over the block's 256 codes,
// s_wmin exchange + 2 barriers/M-tile); with 4 blocks/CU resident the barrier
// drain overlaps with other blocks. Exact re-evals go to LDS s_best, then one
// global u64 atomicMin per point merges the 4 chunks.
__global__ void __launch_bounds__(256, 4) vq_partial(
    const float* __restrict__ inputs, const float* __restrict__ embedT,
    const unsigned short* __restrict__ embedTb, const float* __restrict__ en2,
    const float* __restrict__ fn2, const int* __restrict__ en2max_bits,
    unsigned long long* __restrict__ best) {
  __shared__ unsigned long long s_best[PTS_PER_BLK];
  __shared__ unsigned s_wl[WL_CAP];
  __shared__ int s_wcount;
  __shared__ float s_fn2[PTS_PER_BLK];
  __shared__ float s_wmin[4][16];

  const int tid = threadIdx.x;
  const int w = tid >> 6;
  const int l = tid & 63;
  const int l15 = l & 15;
  const int lg = l >> 4;                 // quad-group 0..3
  const int chunk = blockIdx.x / PTILES;
  const int ptile = blockIdx.x % PTILES;
  const int p0blk = ptile * PTS_PER_BLK;
  const int cb = chunk * 256 + w * 64;   // this wave's first code

  s_best[tid] = ~0ull;
  if (tid == 0) s_wcount = 0;
  s_fn2[tid] = fn2[p0blk + tid];

  const float en2max = __int_as_float(*en2max_bits);

  // B fragments: B[k][n], lane holds n = cb+16t+l15, k = kf*32 + lg*8 + j.
  bf16x8 bfr[NT][2];
  float en2v[NT];
#pragma unroll
  for (int t = 0; t < NT; ++t) {
    const bf16x8* bp = reinterpret_cast<const bf16x8*>(
        embedTb + (size_t)(cb + 16 * t + l15) * D + lg * 8);
    bfr[t][0] = bp[0];   // k in [lg*8, lg*8+8)
    bfr[t][1] = bp[4];   // +32 shorts -> k in [32+lg*8, ...)
    en2v[t] = en2[cb + 16 * t + l15];
  }

  __syncthreads();  // s_best / s_wcount / s_fn2 ready

#pragma unroll 1
  for (int mt = 0; mt < MTILES; ++mt) {
    const int p0 = p0blk + mt * 16;
    // A fragment: lane holds m = p0+l15, k = kf*32 + lg*8 + j (fp32->bf16 inline).
    const float* arow = inputs + (size_t)(p0 + l15) * D + lg * 8;
    float4 a0 = *reinterpret_cast<const float4*>(arow + 0);
    float4 a1 = *reinterpret_cast<const float4*>(arow + 4);
    float4 a2 = *reinterpret_cast<const float4*>(arow + 32);
    float4 a3 = *reinterpret_cast<const float4*>(arow + 36);
    bf16x8 af0, af1;
    af0[0] = f2bf(a0.x); af0[1] = f2bf(a0.y); af0[2] = f2bf(a0.z); af0[3] = f2bf(a0.w);
    af0[4] = f2bf(a1.x); af0[5] = f2bf(a1.y); af0[6] = f2bf(a1.z); af0[7] = f2bf(a1.w);
    af1[0] = f2bf(a2.x); af1[1] = f2bf(a2.y); af1[2] = f2bf(a2.z); af1[3] = f2bf(a2.w);
    af1[4] = f2bf(a3.x); af1[5] = f2bf(a3.y); af1[6] = f2bf(a3.z); af1[7] = f2bf(a3.w);

    f32x4 acc[NT];
#pragma unroll
    for (int t = 0; t < NT; ++t) acc[t] = (f32x4){0.f, 0.f, 0.f, 0.f};
#pragma unroll
    for (int t = 0; t < NT; ++t)
      acc[t] = __builtin_amdgcn_mfma_f32_16x16x32_bf16(af0, bfr[t][0], acc[t], 0, 0, 0);
#pragma unroll
    for (int t = 0; t < NT; ++t)
      acc[t] = __builtin_amdgcn_mfma_f32_16x16x32_bf16(af1, bfr[t][1], acc[t], 0, 0, 0);

    // C/D layout: row(point) = lg*4 + reg, col(code) = l15 [m89/m91-verified].
    float fnv[4];
#pragma unroll
    for (int r = 0; r < 4; ++r) fnv[r] = s_fn2[mt * 16 + lg * 4 + r];
#pragma unroll
    for (int t = 0; t < NT; ++t)
#pragma unroll
      for (int r = 0; r < 4; ++r)
        acc[t][r] = fmaf(-2.f, acc[t][r], fnv[r]) + en2v[t];

    // Block-global screening min over this block's 256 codes (tight worklist):
    // lane-local over t, butterfly over 16 cols, LDS exchange over 4 waves.
    float m[4];
#pragma unroll
    for (int r = 0; r < 4; ++r) {
      float mm = acc[0][r];
#pragma unroll
      for (int t = 1; t < NT; ++t) mm = fminf(mm, acc[t][r]);
#pragma unroll
      for (int s = 1; s < 16; s <<= 1) mm = fminf(mm, __shfl_xor(mm, s, 16));
      m[r] = mm;
    }
    if (l15 == 0) {
#pragma unroll
      for (int r = 0; r < 4; ++r) s_wmin[w][lg * 4 + r] = m[r];
    }
    __syncthreads();
    float thr[4];
#pragma unroll
    for (int r = 0; r < 4; ++r) {
      int q = lg * 4 + r;
      float fm = fminf(fminf(s_wmin[0][q], s_wmin[1][q]), fminf(s_wmin[2][q], s_wmin[3][q]));
      // margin >= 2*|d~ - d| bound: bf16 u=2^-8 -> 2*2^-7*sqrt(fn2*en2) + slack, x2 safety.
      // Per-block containment: the chunk holding the true argmin admits it vs
      // its own block-min + margin, so the union over chunks is correct.
      thr[r] = fm + (0.03125f * sqrtf(fnv[r] * en2max) + 0.01f);
    }
#pragma unroll
    for (int t = 0; t < NT; ++t)
#pragma unroll
      for (int r = 0; r < 4; ++r)
        if (acc[t][r] <= thr[r]) {
          int pl = mt * 16 + lg * 4 + r;
          int c = cb + 16 * t + l15;
          int pos = atomicAdd(&s_wcount, 1);
          if (pos < WL_CAP) s_wl[pos] = (unsigned)((pl << 10) | c);
          else evalExact(inputs, embedT, en2, s_fn2, p0blk, pl, c, s_best);  // overflow
        }
    __syncthreads();  // s_wmin reused next M-tile
  }

  // Exact re-eval of the worklist (parallel across the block).
  int wc = s_wcount; if (wc > WL_CAP) wc = WL_CAP;
  for (int i = tid; i < wc; i += 256)
    evalExact(inputs, embedT, en2, s_fn2, p0blk, (int)(s_wl[i] >> 10), (int)(s_wl[i] & 1023), s_best);
  __syncthreads();

  // Merge this chunk's result into the global per-point best.
  atomicMin(&best[p0blk + tid], s_best[tid]);
}

// K2 (finalize): stream points; gather the winning code row; write all outputs
// with the proven coalesced 4-lane-cooperative pattern.
__global__ void __launch_bounds__(256) vq_finalize(
    const float* __restrict__ inputs, const float* __restrict__ embedT,
    const unsigned long long* __restrict__ best,
    float* __restrict__ out_q, float* __restrict__ out_codes,
    float* __restrict__ out_idx) {
  const int tid = threadIdx.x;
  const int p0blk = blockIdx.x * 256;
  const int sub = tid & 3;
#pragma unroll 1
  for (int pass = 0; pass < 4; ++pass) {
    int pl = pass * 64 + (tid >> 2);
    int p = p0blk + pl;
    unsigned long long key = best[p];
    int c = (int)(unsigned)(key & 0xFFFFFFFFu);
    const f32x4* qrow = reinterpret_cast<const f32x4*>(embedT + (size_t)c * D);
    const f32x4* frow = reinterpret_cast<const f32x4*>(inputs + (size_t)p * D);
    f32x4* oq = reinterpret_cast<f32x4*>(out_q + (size_t)p * D);
    f32x4* oc = reinterpret_cast<f32x4*>(out_codes + (size_t)p * 2 * D);
#pragma unroll
    for (int j = 0; j < 4; ++j) {
      int i4 = j * 4 + sub;
      f32x4 qv = qrow[i4];
      f32x4 fv = frow[i4];
      oq[i4] = qv;
      oc[i4] = fv;
      oc[16 + i4] = qv;
    }
    if (sub == 0) out_idx[p] = (float)c;
  }
}

extern "C" void kernel_launch(void* const* d_in, const int* in_sizes, int n_in,
                              void* d_out, int out_size, void* d_ws, size_t ws_size,
                              hipStream_t stream) {
  const float* inputs = (const float*)d_in[0];
  const float* embed  = (const float*)d_in[1];
  int N = in_sizes[0] / D;  // 131072

  // ws layout (~1.92 MB): best first for 8B alignment.
  unsigned long long* best = (unsigned long long*)d_ws;               // 1 MB
  float* embedT            = (float*)(best + N);                      // 256 KB
  unsigned short* embedTb  = (unsigned short*)(embedT + KCODES * D);  // 128 KB
  float* en2               = (float*)(embedTb + KCODES * D);          // 4 KB
  float* fn2               = en2 + KCODES;                            // 512 KB
  int* en2max_bits         = (int*)(fn2 + N);                         // 4 B

  float* out = (float*)d_out;
  float* out_q     = out;                      // [N, 64]
  float* out_codes = out + (size_t)N * D;      // [N, 128]
  float* out_idx   = out + (size_t)N * D * 3;  // [N]

  vq_prep<<<KCODES / 256 + N / 256, 256, 0, stream>>>(embed, inputs, embedT, embedTb,
                                                      en2, en2max_bits, fn2, best);
  vq_partial<<<CODE_CHUNKS * PTILES, 256, 0, stream>>>(inputs, embedT, embedTb, en2,
                                                       fn2, en2max_bits, best);
  vq_finalize<<<N / 256, 256, 0, stream>>>(inputs, embedT, best, out_q, out_codes, out_idx);
}

// Round 4
// 314.355 us; speedup vs baseline: 1.3157x; 1.0834x over previous
//
#include <hip/hip_runtime.h>

#define D 64
#define KCODES 1024
#define PTS_PER_BLK 256
#define MTILES 16        // 16 points per M-tile x 16 tiles = 256 points/block
#define NT 4             // 4 N-tiles of 16 codes per wave = 64 codes/wave, 256/block
#define CODE_CHUNKS 4    // 4 blocks cover the 1024 codes for one point-tile
#define PTILES 512       // N / PTS_PER_BLK
#define WL_CAP 2048

typedef _Float16 f16x8 __attribute__((ext_vector_type(8)));
typedef float f32x4 __attribute__((ext_vector_type(4)));

static __device__ __forceinline__ unsigned short f2h(float f) {  // RNE fp32->fp16
  _Float16 h = (_Float16)f;
  return __builtin_bit_cast(unsigned short, h);
}

// Exact fp32 distance, bit-identical to the original formula (4-chain fma, then
// fma(-2,dot,fn2)+en2). Packed-key atomicMin: ties -> smaller idx = first occurrence.
static __device__ __forceinline__ void evalExact(const float* __restrict__ inputs,
                                                 const float* __restrict__ embedT,
                                                 const float* __restrict__ en2,
                                                 const float* s_fn2,
                                                 int p0blk, int pl, int c,
                                                 unsigned long long* s_best) {
  int p = p0blk + pl;
  const float* f = inputs + (size_t)p * D;
  const float* e = embedT + (size_t)c * D;
  float a0 = 0.f, a1 = 0.f, a2 = 0.f, a3 = 0.f;
#pragma unroll
  for (int d = 0; d < D; d += 4) {
    a0 = fmaf(f[d + 0], e[d + 0], a0);
    a1 = fmaf(f[d + 1], e[d + 1], a1);
    a2 = fmaf(f[d + 2], e[d + 2], a2);
    a3 = fmaf(f[d + 3], e[d + 3], a3);
  }
  float dot = (a0 + a1) + (a2 + a3);
  float dist = fmaf(-2.f, dot, s_fn2[pl]) + en2[c];
  unsigned long long key = ((unsigned long long)__float_as_uint(dist) << 32) | (unsigned)c;
  atomicMin(&s_best[pl], key);
}

// Merged prep. Blocks 0..3: embed [64][1024] -> embedT fp32 [1024][64],
// embedTh fp16 [1024][64], en2[k] (sequential-fma order), en2max (atomicMax
// on bits; ws poison is a negative int so any positive value wins).
// Blocks 4..515: fn2[p] (original float4 sequential-fma order -> bit-identical)
// and best[p] = ~0ull init.
__global__ void __launch_bounds__(256) vq_prep(const float* __restrict__ embed,
                                               const float* __restrict__ inputs,
                                               float* __restrict__ embedT,
                                               unsigned short* __restrict__ embedTh,
                                               float* __restrict__ en2,
                                               int* __restrict__ en2max_bits,
                                               float* __restrict__ fn2,
                                               unsigned long long* __restrict__ best) {
  const int bid = blockIdx.x;
  const int tid = threadIdx.x;
  if (bid < KCODES / 256) {
    int k = bid * 256 + tid;
    float row[D];
    float s = 0.f;
#pragma unroll
    for (int d = 0; d < D; ++d) {
      float e = embed[d * KCODES + k];   // coalesced along k
      row[d] = e;
      s = fmaf(e, e, s);
    }
    en2[k] = s;
    float4* o4 = reinterpret_cast<float4*>(embedT + (size_t)k * D);
#pragma unroll
    for (int j = 0; j < 16; ++j)
      o4[j] = make_float4(row[4 * j], row[4 * j + 1], row[4 * j + 2], row[4 * j + 3]);
    unsigned us[32];
#pragma unroll
    for (int j = 0; j < 32; ++j) {
      unsigned lo = f2h(row[2 * j]);
      unsigned hi = f2h(row[2 * j + 1]);
      us[j] = lo | (hi << 16);
    }
    uint4* ob = reinterpret_cast<uint4*>(embedTh + (size_t)k * D);
#pragma unroll
    for (int j = 0; j < 8; ++j)
      ob[j] = make_uint4(us[4 * j], us[4 * j + 1], us[4 * j + 2], us[4 * j + 3]);
    float m = s;
#pragma unroll
    for (int off = 32; off; off >>= 1) m = fmaxf(m, __shfl_down(m, off, 64));
    if ((tid & 63) == 0) atomicMax(en2max_bits, __float_as_int(m));
  } else {
    int p = (bid - KCODES / 256) * 256 + tid;
    const float4* i4 = reinterpret_cast<const float4*>(inputs + (size_t)p * D);
    float s = 0.f;
#pragma unroll
    for (int j = 0; j < 16; ++j) {
      float4 v = i4[j];
      s = fmaf(v.x, v.x, s); s = fmaf(v.y, v.y, s);
      s = fmaf(v.z, v.z, s); s = fmaf(v.w, v.w, s);
    }
    fn2[p] = s;
    best[p] = ~0ull;
  }
}

// K1 (partial): block = (code-chunk, point-tile); 256 points x 256 codes.
// R4 changes (screen-tightness round):
//  - approx pass bf16 -> fp16 (mfma_f32_16x16x32_f16; C/D layout is
//    dtype-independent). u: 2^-8 -> 2^-11 => margin shrinks 8x =>
//    ~8x fewer exact re-evals + worklist atomics.
//  - screen on d' = en2 - 2*dot (fn2 is per-point constant; identical
//    candidate set, one less add per element)
//  - s_wmin double-buffered on mt&1 -> 1 barrier per M-tile instead of 2
__global__ void __launch_bounds__(256, 4) vq_partial(
    const float* __restrict__ inputs, const float* __restrict__ embedT,
    const unsigned short* __restrict__ embedTh, const float* __restrict__ en2,
    const float* __restrict__ fn2, const int* __restrict__ en2max_bits,
    unsigned long long* __restrict__ best) {
  __shared__ unsigned long long s_best[PTS_PER_BLK];
  __shared__ unsigned s_wl[WL_CAP];
  __shared__ int s_wcount;
  __shared__ float s_fn2[PTS_PER_BLK];
  __shared__ float s_wmin[2][4][16];

  const int tid = threadIdx.x;
  const int w = tid >> 6;
  const int l = tid & 63;
  const int l15 = l & 15;
  const int lg = l >> 4;                 // quad-group 0..3
  const int chunk = blockIdx.x / PTILES;
  const int ptile = blockIdx.x % PTILES;
  const int p0blk = ptile * PTS_PER_BLK;
  const int cb = chunk * 256 + w * 64;   // this wave's first code

  s_best[tid] = ~0ull;
  if (tid == 0) s_wcount = 0;
  s_fn2[tid] = fn2[p0blk + tid];

  const float en2max = __int_as_float(*en2max_bits);

  // B fragments: B[k][n], lane holds n = cb+16t+l15, k = kf*32 + lg*8 + j.
  // embedTh row n is contiguous in k -> one 16B load per frag. L2-hot.
  f16x8 bfr[NT][2];
  float en2v[NT];
#pragma unroll
  for (int t = 0; t < NT; ++t) {
    const f16x8* bp = reinterpret_cast<const f16x8*>(
        embedTh + (size_t)(cb + 16 * t + l15) * D + lg * 8);
    bfr[t][0] = bp[0];   // k in [lg*8, lg*8+8)
    bfr[t][1] = bp[4];   // +32 halves -> k in [32+lg*8, ...)
    en2v[t] = en2[cb + 16 * t + l15];
  }

  __syncthreads();  // s_best / s_wcount / s_fn2 ready

#pragma unroll 1
  for (int mt = 0; mt < MTILES; ++mt) {
    const int p0 = p0blk + mt * 16;
    // A fragment: lane holds m = p0+l15, k = kf*32 + lg*8 + j (fp32->fp16 RNE cast).
    const float* arow = inputs + (size_t)(p0 + l15) * D + lg * 8;
    float4 a0 = *reinterpret_cast<const float4*>(arow + 0);
    float4 a1 = *reinterpret_cast<const float4*>(arow + 4);
    float4 a2 = *reinterpret_cast<const float4*>(arow + 32);
    float4 a3 = *reinterpret_cast<const float4*>(arow + 36);
    f16x8 af0, af1;
    af0[0] = (_Float16)a0.x; af0[1] = (_Float16)a0.y; af0[2] = (_Float16)a0.z; af0[3] = (_Float16)a0.w;
    af0[4] = (_Float16)a1.x; af0[5] = (_Float16)a1.y; af0[6] = (_Float16)a1.z; af0[7] = (_Float16)a1.w;
    af1[0] = (_Float16)a2.x; af1[1] = (_Float16)a2.y; af1[2] = (_Float16)a2.z; af1[3] = (_Float16)a2.w;
    af1[4] = (_Float16)a3.x; af1[5] = (_Float16)a3.y; af1[6] = (_Float16)a3.z; af1[7] = (_Float16)a3.w;

    f32x4 acc[NT];
#pragma unroll
    for (int t = 0; t < NT; ++t) acc[t] = (f32x4){0.f, 0.f, 0.f, 0.f};
#pragma unroll
    for (int t = 0; t < NT; ++t)
      acc[t] = __builtin_amdgcn_mfma_f32_16x16x32_f16(af0, bfr[t][0], acc[t], 0, 0, 0);
#pragma unroll
    for (int t = 0; t < NT; ++t)
      acc[t] = __builtin_amdgcn_mfma_f32_16x16x32_f16(af1, bfr[t][1], acc[t], 0, 0, 0);

    // C/D layout: row(point) = lg*4 + reg, col(code) = l15 [m89/m91-verified].
    // Screened quantity d' = en2 - 2*dot (drop the per-point fn2 constant).
#pragma unroll
    for (int t = 0; t < NT; ++t)
#pragma unroll
      for (int r = 0; r < 4; ++r)
        acc[t][r] = fmaf(-2.f, acc[t][r], en2v[t]);

    // Block-global screening min over this block's 256 codes (tight worklist):
    // lane-local over t, butterfly over 16 cols, LDS exchange over 4 waves.
    float m[4];
#pragma unroll
    for (int r = 0; r < 4; ++r) {
      float mm = acc[0][r];
#pragma unroll
      for (int t = 1; t < NT; ++t) mm = fminf(mm, acc[t][r]);
#pragma unroll
      for (int s = 1; s < 16; s <<= 1) mm = fminf(mm, __shfl_xor(mm, s, 16));
      m[r] = mm;
    }
    if (l15 == 0) {
#pragma unroll
      for (int r = 0; r < 4; ++r) s_wmin[mt & 1][w][lg * 4 + r] = m[r];
    }
    __syncthreads();  // single barrier: next tile uses the other buffer
    float fnv[4];
#pragma unroll
    for (int r = 0; r < 4; ++r) fnv[r] = s_fn2[mt * 16 + lg * 4 + r];
    float thr[4];
#pragma unroll
    for (int r = 0; r < 4; ++r) {
      int q = lg * 4 + r;
      float fm = fminf(fminf(s_wmin[mt & 1][0][q], s_wmin[mt & 1][1][q]),
                       fminf(s_wmin[mt & 1][2][q], s_wmin[mt & 1][3][q]));
      // margin >= 2*|d'~ - d'|: fp16 u=2^-11, products exact in fp32 ->
      // |err| <= 4u*sqrt(fn2*en2max) = 2^-9*sqrt(...); x2 safety -> 2^-8.
      // + 0.01 slack for fp32 accumulation-order differences.
      thr[r] = fm + (0.00390625f * sqrtf(fnv[r] * en2max) + 0.01f);
    }
#pragma unroll
    for (int t = 0; t < NT; ++t)
#pragma unroll
      for (int r = 0; r < 4; ++r)
        if (acc[t][r] <= thr[r]) {
          int pl = mt * 16 + lg * 4 + r;
          int c = cb + 16 * t + l15;
          int pos = atomicAdd(&s_wcount, 1);
          if (pos < WL_CAP) s_wl[pos] = (unsigned)((pl << 10) | c);
          else evalExact(inputs, embedT, en2, s_fn2, p0blk, pl, c, s_best);  // overflow
        }
  }

  __syncthreads();  // worklist complete

  // Exact re-eval of the worklist (parallel across the block).
  int wc = s_wcount; if (wc > WL_CAP) wc = WL_CAP;
  for (int i = tid; i < wc; i += 256)
    evalExact(inputs, embedT, en2, s_fn2, p0blk, (int)(s_wl[i] >> 10), (int)(s_wl[i] & 1023), s_best);
  __syncthreads();

  // Merge this chunk's result into the global per-point best.
  atomicMin(&best[p0blk + tid], s_best[tid]);
}

// K2 (finalize): stream points; gather the winning code row; write all outputs
// with the proven coalesced 4-lane-cooperative pattern.
__global__ void __launch_bounds__(256) vq_finalize(
    const float* __restrict__ inputs, const float* __restrict__ embedT,
    const unsigned long long* __restrict__ best,
    float* __restrict__ out_q, float* __restrict__ out_codes,
    float* __restrict__ out_idx) {
  const int tid = threadIdx.x;
  const int p0blk = blockIdx.x * 256;
  const int sub = tid & 3;
#pragma unroll 1
  for (int pass = 0; pass < 4; ++pass) {
    int pl = pass * 64 + (tid >> 2);
    int p = p0blk + pl;
    unsigned long long key = best[p];
    int c = (int)(unsigned)(key & 0xFFFFFFFFu);
    const f32x4* qrow = reinterpret_cast<const f32x4*>(embedT + (size_t)c * D);
    const f32x4* frow = reinterpret_cast<const f32x4*>(inputs + (size_t)p * D);
    f32x4* oq = reinterpret_cast<f32x4*>(out_q + (size_t)p * D);
    f32x4* oc = reinterpret_cast<f32x4*>(out_codes + (size_t)p * 2 * D);
#pragma unroll
    for (int j = 0; j < 4; ++j) {
      int i4 = j * 4 + sub;
      f32x4 qv = qrow[i4];
      f32x4 fv = frow[i4];
      oq[i4] = qv;
      oc[i4] = fv;
      oc[16 + i4] = qv;
    }
    if (sub == 0) out_idx[p] = (float)c;
  }
}

extern "C" void kernel_launch(void* const* d_in, const int* in_sizes, int n_in,
                              void* d_out, int out_size, void* d_ws, size_t ws_size,
                              hipStream_t stream) {
  const float* inputs = (const float*)d_in[0];
  const float* embed  = (const float*)d_in[1];
  int N = in_sizes[0] / D;  // 131072

  // ws layout (~1.9 MB): best first for 8B alignment.
  unsigned long long* best  = (unsigned long long*)d_ws;              // 1 MB
  float* embedT             = (float*)(best + N);                     // 256 KB
  unsigned short* embedTh   = (unsigned short*)(embedT + KCODES * D); // 128 KB (fp16)
  float* en2                = (float*)(embedTh + KCODES * D);         // 4 KB
  float* fn2                = en2 + KCODES;                           // 512 KB
  int* en2max_bits          = (int*)(fn2 + N);                        // 4 B

  float* out = (float*)d_out;
  float* out_q     = out;                      // [N, 64]
  float* out_codes = out + (size_t)N * D;      // [N, 128]
  float* out_idx   = out + (size_t)N * D * 3;  // [N]

  vq_prep<<<KCODES / 256 + N / 256, 256, 0, stream>>>(embed, inputs, embedT, embedTh,
                                                      en2, en2max_bits, fn2, best);
  vq_partial<<<CODE_CHUNKS * PTILES, 256, 0, stream>>>(inputs, embedT, embedTh, en2,
                                                       fn2, en2max_bits, best);
  vq_finalize<<<N / 256, 256, 0, stream>>>(inputs, embedT, best, out_q, out_codes, out_idx);
}